// Round 6
// baseline (531.991 us; speedup 1.0000x reference)
//
#include <hip/hip_runtime.h>
#include <math.h>

// B=2, N=512, C=256, POOL=7, NC=81, IMG=1024 ; M = 1024 rois, K1 = 12544
static constexpr int K1 = 12544;

typedef __attribute__((ext_vector_type(8))) _Float16 f16x8;
typedef __attribute__((ext_vector_type(4))) _Float16 f16x4;
typedef __attribute__((ext_vector_type(4))) float f32x4;

// ---------------- ws layout (byte offsets) ----------------
static constexpr size_t REG0_OFF = 0;
static constexpr size_t W1_OFF   = 25690112;   // 25.69 MB fp16 w1
static constexpr size_t PART_OFF = 51380224;   // 32 MB split-K partials
static constexpr size_t H1_OFF   = 84934656;   // 4 MB fp32
// inside REG0, valid only after conv1 gemm has consumed ph:
static constexpr size_t S1H_OFF  = 0;          // 2 MB fp16
static constexpr size_t S2H_OFF  = 2097152;    // 2 MB fp16
static constexpr size_t W2H_OFF  = 4194304;    // 2 MB fp16
static constexpr size_t WCAT_OFF = 6291456;    // 1 MB fp16 (512x1024)
static constexpr size_t MW1_OFF  = 7340032;    // 0.33 MB fp32
// bn stats live in the LAST 16KB of PART (84918272..84934656): PART is dead
// during prep (safe to zero there); conv1 writes only splits 0..6 (28MB),
// conv2 16MB, head 16MB -- none reach the tail. NEVER place stats in REG0:
// that region is ph during prep (R5 bug: zeroing there corrupted ph).
static constexpr size_t STAT_OFF = PART_OFF + 33538048;   // = 84918272

// ---------------------------------------------------------------------------
__device__ __forceinline__ void gload16(const void* g, void* l) {
    __builtin_amdgcn_global_load_lds(
        (const __attribute__((address_space(1))) void*)g,
        (__attribute__((address_space(3))) void*)l, 16, 0, 0);
}

// ---------------------------------------------------------------------------
// prep: blocks [0,12544) ROI-align gather -> ph fp16 (geometry inline,
//   lane-pair x-column scheme, 8 ch/thread). blocks [12544,25088) cvt w1;
//   cvt block 0 also zeroes bn1 stat buffers (psum1/psq1, 2048 floats).
// ---------------------------------------------------------------------------
__global__ __launch_bounds__(256) void prep_k(
    const float* __restrict__ p2, const float* __restrict__ p3,
    const float* __restrict__ p4, const float* __restrict__ p5,
    const float* __restrict__ rois, _Float16* __restrict__ ph,
    const float* __restrict__ w1, _Float16* __restrict__ w1h,
    float* __restrict__ zstat)
{
    if (blockIdx.x >= 12544) {
        int bi = blockIdx.x - 12544;
        if (bi == 0) {
            float4 z = make_float4(0.f, 0.f, 0.f, 0.f);
            ((float4*)zstat)[threadIdx.x] = z;
            ((float4*)zstat)[threadIdx.x + 256] = z;
        }
        int i = bi * 256 + threadIdx.x;   // < 3211264
        float4 v = ((const float4*)w1)[i];
        f16x4 h;
        h.x = (_Float16)v.x; h.y = (_Float16)v.y;
        h.z = (_Float16)v.z; h.w = (_Float16)v.w;
        ((f16x4*)w1h)[i] = h;
        return;
    }
    const int q  = threadIdx.x & 1;                 // x-column select
    const int gp = blockIdx.x * 128 + (threadIdx.x >> 1);   // pair id
    const int n  = gp / 1568;                       // 1568 = 49 pos * 32 cgroups
    const int r  = gp - n * 1568;
    const int cg = r / 49;
    const int pos = r - cg * 49;
    const int px = pos % 7, py = pos / 7;

    // inline geometry (8x redundant across cgroups -- cheap vs gather latency)
    float4 rr = ((const float4*)rois)[n];   // (x1, y1, x2, y2)
    float area = (rr.w - rr.y) * (rr.z - rr.x);
    float lf = rintf(log2f(sqrtf(area) / 224.f)) + 4.f;
    int li = (int)fminf(fmaxf(lf, 2.f), 5.f);
    int H = 256 >> (li - 2);

    const float* f; int sh;
    if (li <= 2)      { f = p2; sh = 16; }
    else if (li == 3) { f = p3; sh = 14; }
    else if (li == 4) { f = p4; sh = 12; }
    else              { f = p5; sh = 10; }

    const float inv = 1.f / 1024.f;
    float by1 = rr.y * inv, bx1 = rr.x * inv, by2 = rr.w * inv, bx2 = rr.z * inv;
    float Hm1 = (float)(H - 1);
    float gy = (float)py / 6.f;
    float gx = (float)px / 6.f;
    float ys = (by1 + gy * (by2 - by1)) * Hm1;
    float xs = (bx1 + gx * (bx2 - bx1)) * Hm1;
    float y0f = floorf(ys), x0f = floorf(xs);
    float ly = ys - y0f, lx = xs - x0f;
    int iy0 = (int)fminf(fmaxf(y0f,       0.f), Hm1);
    int iy1 = (int)fminf(fmaxf(y0f + 1.f, 0.f), Hm1);
    int ix  = q ? (int)fminf(fmaxf(x0f + 1.f, 0.f), Hm1)
                : (int)fminf(fmaxf(x0f,       0.f), Hm1);
    bool valid = (ys >= 0.f) && (ys <= Hm1) && (xs >= 0.f) && (xs <= Hm1);
    float vm = valid ? 1.f : 0.f;
    float wx = q ? lx : (1.f - lx);
    const float w0  = (1.f - ly) * wx * vm;
    const float w1w = ly * wx * vm;
    const int off0 = iy0 * H + ix;
    const int off1 = iy1 * H + ix;

    const size_t cs = (size_t)1 << sh;              // channel stride (floats)
    const float* fb = f + (size_t)(cg * 8) * cs;

    float v0[8], v1[8];
    #pragma unroll
    for (int cc = 0; cc < 8; cc++) {
        v0[cc] = fb[(size_t)cc * cs + off0];
        v1[cc] = fb[(size_t)cc * cs + off1];
    }

    _Float16* pb = ph + (size_t)n * 12544 + (size_t)(cg * 8) * 49 + pos;
    #pragma unroll
    for (int cc = 0; cc < 8; cc++) {
        float t = v0[cc] * w0 + v1[cc] * w1w;
        t += __shfl_xor(t, 1);                      // combine x0+x1 columns
        if ((cc >> 2) == q) pb[cc * 49] = (_Float16)t;
    }
}

// ---------------------------------------------------------------------------
// fp16 MFMA GEMM: Cpart[s] = Ah * Bh^T (per-split chunk), plain stores.
// 128x128 tile, 4 waves (2x2 of 64x64), BK=64, 8-slot XOR-swizzled LDS.
// XCD-aware decode: row = bx&7 pins each A-panel row to one XCD's L2.
// kChunk must be a multiple of 64. grid (8*tilesN, nSplit).
// ---------------------------------------------------------------------------
__global__ __launch_bounds__(256) void gemm16h(
    const _Float16* __restrict__ Ah, const _Float16* __restrict__ Bh,
    float* __restrict__ Cpart, int Nn, int lda, int ldb, int kChunk)
{
    __shared__ _Float16 sA[128][64];
    __shared__ _Float16 sB[128][64];

    const int tid  = threadIdx.x;
    const int lane = tid & 63;
    const int wave = tid >> 6;
    const int tm0  = (blockIdx.x & 7) * 128;    // XCD-pinned A-panel row
    const int tn0  = (blockIdx.x >> 3) * 128;
    const int k0   = blockIdx.y * kChunk;

    const int wm = (wave >> 1) * 64;
    const int wn = (wave & 1) * 64;

    const int r8  = lane >> 3;
    const int skh = ((lane & 7) ^ r8) * 8;          // halfs

    f32x4 acc[4][4];
    #pragma unroll
    for (int i = 0; i < 4; i++)
        #pragma unroll
        for (int j = 0; j < 4; j++) acc[i][j] = (f32x4){0.f, 0.f, 0.f, 0.f};

    const int mrow = wm + (lane & 15);
    const int ncol = wn + (lane & 15);
    const int gk   = lane >> 4;                     // k-subgroup 0..3
    const int swz  = lane & 7;                      // == mrow&7 == ncol&7

    for (int kt = 0; kt < kChunk; kt += 64) {
        const int kb = k0 + kt;
        #pragma unroll
        for (int i = 0; i < 4; i++) {
            const int rr = wave * 32 + i * 8 + r8;
            gload16(Ah + (size_t)(tm0 + rr) * lda + kb + skh, &sA[wave * 32 + i * 8][0]);
            gload16(Bh + (size_t)(tn0 + rr) * ldb + kb + skh, &sB[wave * 32 + i * 8][0]);
        }
        __syncthreads();

        f16x8 fa[2][4], fb[2][4];
        #pragma unroll
        for (int kk = 0; kk < 2; kk++) {
            const int sc = ((kk * 4 + gk) ^ swz) * 8;   // swizzled halfs col
            #pragma unroll
            for (int t = 0; t < 4; t++) {
                fa[kk][t] = *(const f16x8*)&sA[mrow + t * 16][sc];
                fb[kk][t] = *(const f16x8*)&sB[ncol + t * 16][sc];
            }
        }
        #pragma unroll
        for (int kk = 0; kk < 2; kk++)
            #pragma unroll
            for (int i = 0; i < 4; i++)
                #pragma unroll
                for (int j = 0; j < 4; j++)
                    acc[i][j] = __builtin_amdgcn_mfma_f32_16x16x32_f16(
                        fa[kk][i], fb[kk][j], acc[i][j], 0, 0, 0);
        __syncthreads();
    }

    // C/D layout: col = lane&15, row = (lane>>4)*4 + reg
    float* Cs = Cpart + (size_t)blockIdx.y * 1024 * Nn;
    const int crow = tm0 + wm + (lane >> 4) * 4;
    const int ccol = tn0 + wn + (lane & 15);
    #pragma unroll
    for (int i = 0; i < 4; i++)
        #pragma unroll
        for (int j = 0; j < 4; j++) {
            float* cp = Cs + (size_t)(crow + i * 16) * Nn + (ccol + j * 16);
            #pragma unroll
            for (int rg = 0; rg < 4; rg++)
                cp[(size_t)rg * Nn] = acc[i][j][rg];
        }
}

// ---------------------------------------------------------------------------
// combine NS split-K partials -> h1 (1024x1024); bn stats via device-scope
// atomicAdd into final psum/psq (zeroed by an earlier-stage kernel).
// grid (4 colgroups, 64 rowgroups of 16 rows), 256 thr.
// ---------------------------------------------------------------------------
template<int NS>
__global__ __launch_bounds__(256) void combine_bn_k(
    const float* __restrict__ part, float* __restrict__ h1,
    float* __restrict__ psum, float* __restrict__ psq)
{
    int col = blockIdx.x * 256 + threadIdx.x;
    int r0  = blockIdx.y * 16;
    float s = 0.f, q = 0.f;
    for (int r = 0; r < 16; r++) {
        const float* p0 = part + (size_t)(r0 + r) * 1024 + col;
        float v = p0[0];
        #pragma unroll
        for (int p = 1; p < NS; p++) v += p0[(size_t)p * 1048576];
        h1[(size_t)(r0 + r) * 1024 + col] = v;
        s += v; q += v * v;
    }
    atomicAdd(&psum[col], s);
    atomicAdd(&psq[col], q);
}

// ---------------------------------------------------------------------------
// bn apply (scale/shift computed inline from final psum/psq) + relu -> fp16.
// blocks >= 4096: convert w2/cls/box -> fp16; tail threads zero next-stage
// stat buffers (zstat, 2048 floats) when provided.
// ---------------------------------------------------------------------------
__global__ __launch_bounds__(256) void bn_apply_cvt_k(
    const float* __restrict__ h, const float* __restrict__ psum,
    const float* __restrict__ psq, const float* __restrict__ g,
    const float* __restrict__ b, _Float16* __restrict__ o16,
    const float* __restrict__ w2, const float* __restrict__ cls,
    const float* __restrict__ box, _Float16* __restrict__ w2h,
    _Float16* __restrict__ wcat, float* __restrict__ zstat)
{
    if (blockIdx.x >= 4096) {
        int i = (blockIdx.x - 4096) * 256 + threadIdx.x;
        const int n_w2 = 262144, n_cls = 20736, n_box = 82944;  // float4 units
        if (i >= n_w2 + n_cls + n_box) {
            int j = i - (n_w2 + n_cls + n_box);
            if (zstat && j < 512)
                ((float4*)zstat)[j] = make_float4(0.f, 0.f, 0.f, 0.f);
            return;
        }
        const float* src; _Float16* dst; int j;
        if (i < n_w2)               { src = w2;  dst = w2h;              j = i; }
        else if (i < n_w2 + n_cls)  { src = cls; dst = wcat;             j = i - n_w2; }
        else                        { src = box; dst = wcat + 81 * 1024; j = i - n_w2 - n_cls; }
        float4 v = ((const float4*)src)[j];
        f16x4 hh;
        hh.x = (_Float16)v.x; hh.y = (_Float16)v.y;
        hh.z = (_Float16)v.z; hh.w = (_Float16)v.w;
        ((f16x4*)dst)[j] = hh;
        return;
    }
    int idx = blockIdx.x * 256 + threadIdx.x;
    int col = idx & 1023;
    float mean = psum[col] * (1.f / 1024.f);
    float var  = psq[col] * (1.f / 1024.f) - mean * mean;
    float sc = (1.f / sqrtf(var + 0.001f)) * g[col];
    float sh = b[col] - mean * sc;
    float v = fmaxf(h[idx] * sc + sh, 0.f);
    o16[idx] = (_Float16)v;
}

// ---------------------------------------------------------------------------
// head combine: sum 8 partials (1024x512), add cls/box bias, route to
// logits/bbox, and compute softmax -> probs. One wave per row, 4 rows/block.
// ---------------------------------------------------------------------------
__global__ __launch_bounds__(256) void head_combine_k(
    const float* __restrict__ part, const float* __restrict__ cls_b,
    const float* __restrict__ box_b, float* __restrict__ o_logits,
    float* __restrict__ o_probs, float* __restrict__ o_bbox)
{
    int wave = threadIdx.x >> 6, lane = threadIdx.x & 63;
    int row = blockIdx.x * 4 + wave;
    const float* pr = part + (size_t)row * 512;

    float lv0;
    {
        float s = pr[lane];
        #pragma unroll
        for (int p = 1; p < 8; p++) s += pr[(size_t)p * 524288 + lane];
        s += cls_b[lane];
        lv0 = s;
        o_logits[(size_t)row * 81 + lane] = s;
    }
    float lv1 = -INFINITY;
    for (int c = lane + 64; c < 405; c += 64) {
        float s = pr[c];
        #pragma unroll
        for (int p = 1; p < 8; p++) s += pr[(size_t)p * 524288 + c];
        if (c < 81) {
            s += cls_b[c];
            lv1 = s;
            o_logits[(size_t)row * 81 + c] = s;
        } else {
            s += box_b[c - 81];
            o_bbox[(size_t)row * 324 + (c - 81)] = s;
        }
    }
    float m = fmaxf(lv0, lv1);
    for (int o = 32; o; o >>= 1) m = fmaxf(m, __shfl_xor(m, o));
    float e0 = expf(lv0 - m);
    float e1 = (lane < 17) ? expf(lv1 - m) : 0.f;
    float s = e0 + e1;
    for (int o = 32; o; o >>= 1) s += __shfl_xor(s, o);
    float rs = 1.f / s;
    o_probs[(size_t)row * 81 + lane] = e0 * rs;
    if (lane < 17) o_probs[(size_t)row * 81 + lane + 64] = e1 * rs;
}

// ---------------------------------------------------------------------------
// fp32 tiled GEMM (tf path): C = A * B^T, full-K, fused bias + leaky epilogue
// ---------------------------------------------------------------------------
template<int BM, int BN, int TM, int TN>
__global__ __launch_bounds__(256) void gemm_nt(
    const float* __restrict__ A, const float* __restrict__ B,
    const float* __restrict__ bias, float* __restrict__ outF,
    int Mm, int Nn, int lda, int ldb, int kTot, int tilesN)
{
    constexpr int BK = 16;
    __shared__ float As[BK][BM + 4];
    __shared__ float Bs[BK][BN + 4];

    const int tile = blockIdx.x;
    const int tm0  = (tile / tilesN) * BM;
    const int tn0  = (tile % tilesN) * BN;
    const int tid  = threadIdx.x;
    const int tx   = tid % (BN / TN);
    const int ty   = tid / (BN / TN);

    constexpr int AVEC = BM * BK / (256 * 4);
    constexpr int BVEC = BN * BK / (256 * 4);
    const int lrow = tid >> 2;
    const int lkq  = (tid & 3) * 4;

    float acc[TM][TN];
    #pragma unroll
    for (int i = 0; i < TM; i++)
        #pragma unroll
        for (int j = 0; j < TN; j++) acc[i][j] = 0.f;

    for (int kt = 0; kt < kTot; kt += BK) {
        #pragma unroll
        for (int v = 0; v < AVEC; v++) {
            int row = lrow + v * 64;
            int gm = tm0 + row;
            float4 val = make_float4(0.f, 0.f, 0.f, 0.f);
            if (gm < Mm) val = *(const float4*)&A[(size_t)gm * lda + kt + lkq];
            As[lkq + 0][row] = val.x; As[lkq + 1][row] = val.y;
            As[lkq + 2][row] = val.z; As[lkq + 3][row] = val.w;
        }
        #pragma unroll
        for (int v = 0; v < BVEC; v++) {
            int row = lrow + v * 64;
            int gn = tn0 + row;
            float4 val = make_float4(0.f, 0.f, 0.f, 0.f);
            if (gn < Nn) val = *(const float4*)&B[(size_t)gn * ldb + kt + lkq];
            Bs[lkq + 0][row] = val.x; Bs[lkq + 1][row] = val.y;
            Bs[lkq + 2][row] = val.z; Bs[lkq + 3][row] = val.w;
        }
        __syncthreads();
        #pragma unroll
        for (int kk = 0; kk < BK; kk++) {
            float a[TM], b[TN];
            #pragma unroll
            for (int i = 0; i < TM; i++) a[i] = As[kk][ty * TM + i];
            #pragma unroll
            for (int j = 0; j < TN; j++) b[j] = Bs[kk][tx * TN + j];
            #pragma unroll
            for (int i = 0; i < TM; i++)
                #pragma unroll
                for (int j = 0; j < TN; j++)
                    acc[i][j] += a[i] * b[j];
        }
        __syncthreads();
    }

    #pragma unroll
    for (int i = 0; i < TM; i++) {
        int gm = tm0 + ty * TM + i;
        if (gm >= Mm) continue;
        #pragma unroll
        for (int j = 0; j < TN; j++) {
            int gn = tn0 + tx * TN + j;
            if (gn < Nn) {
                float v = acc[i][j] + bias[gn];
                v = (v >= 0.f) ? v : 0.01f * v;
                outF[(size_t)gm * Nn + gn] = v;
            }
        }
    }
}

// ---------------------------------------------------------------------------
extern "C" void kernel_launch(void* const* d_in, const int* in_sizes, int n_in,
                              void* d_out, int out_size, void* d_ws, size_t ws_size,
                              hipStream_t stream)
{
    const float* p2      = (const float*)d_in[0];
    const float* p3      = (const float*)d_in[1];
    const float* p4      = (const float*)d_in[2];
    const float* p5      = (const float*)d_in[3];
    const float* rois    = (const float*)d_in[4];
    const float* conv1_w = (const float*)d_in[5];
    const float* bn1_g   = (const float*)d_in[7];
    const float* bn1_b   = (const float*)d_in[8];
    const float* conv2_w = (const float*)d_in[9];
    const float* bn2_g   = (const float*)d_in[11];
    const float* bn2_b   = (const float*)d_in[12];
    const float* cls_w   = (const float*)d_in[13];
    const float* cls_b   = (const float*)d_in[14];
    const float* box_w   = (const float*)d_in[15];
    const float* box_b   = (const float*)d_in[16];
    const float* tf1_w   = (const float*)d_in[17];
    const float* tf1_b   = (const float*)d_in[18];
    const float* tf2_w   = (const float*)d_in[19];
    const float* tf2_b   = (const float*)d_in[20];

    char* wsb = (char*)d_ws;
    float* out = (float*)d_out;

    _Float16* ph   = (_Float16*)(wsb + REG0_OFF);
    _Float16* w1h  = (_Float16*)(wsb + W1_OFF);
    float*    part = (float*)(wsb + PART_OFF);
    float*    h1   = (float*)(wsb + H1_OFF);
    _Float16* s1h  = (_Float16*)(wsb + S1H_OFF);
    _Float16* s2h  = (_Float16*)(wsb + S2H_OFF);
    _Float16* w2h  = (_Float16*)(wsb + W2H_OFF);
    _Float16* wcat = (_Float16*)(wsb + WCAT_OFF);
    float*    mw1  = (float*)(wsb + MW1_OFF);
    float*    psum1 = (float*)(wsb + STAT_OFF);
    float*    psq1  = psum1 + 1024;
    float*    psum2 = psum1 + 2048;
    float*    psq2  = psum1 + 3072;

    float* o_logits = out;
    float* o_probs  = out + 82944;
    float* o_bbox   = out + 165888;
    float* o_mw     = out + 497664;

    // 1) ROI gather (inline geometry) + cvt w1 + zero bn1 stats   [1 launch]
    prep_k<<<25088, 256, 0, stream>>>(p2, p3, p4, p5, rois, ph,
                                      conv1_w, w1h, psum1);

    // 2) conv1: part[s] = ph @ w1h^T  (split-K=7, kChunk=1792=28*64)
    gemm16h<<<dim3(64, 7), 256, 0, stream>>>(ph, w1h, part, 1024, K1, K1, 1792);

    // 3) combine+bn1 stats (atomic) ; apply (inline scale/shift) + cvt
    //    w2/cls/box + zero bn2 stats
    combine_bn_k<7><<<dim3(4, 64), 256, 0, stream>>>(part, h1, psum1, psq1);
    bn_apply_cvt_k<<<5527, 256, 0, stream>>>(h1, psum1, psq1, bn1_g, bn1_b, s1h,
                                             conv2_w, cls_w, box_w, w2h, wcat,
                                             psum2);

    // 4) conv2: part[s] = s1h @ w2h^T  (split-K=4, kChunk=256=4*64)
    gemm16h<<<dim3(64, 4), 256, 0, stream>>>(s1h, w2h, part, 1024, 1024, 1024, 256);

    // 5) combine+bn2 (atomic) ; apply -> s2h
    combine_bn_k<4><<<dim3(4, 64), 256, 0, stream>>>(part, h1, psum2, psq2);
    bn_apply_cvt_k<<<4096, 256, 0, stream>>>(h1, psum2, psq2, bn2_g, bn2_b, s2h,
                                             nullptr, nullptr, nullptr, nullptr,
                                             nullptr, nullptr);

    // 6) head: part[s] = s2h @ wcat^T (N=512 padded, split-K=8)
    gemm16h<<<dim3(32, 8), 256, 0, stream>>>(s2h, wcat, part, 512, 1024, 1024, 128);
    head_combine_k<<<256, 256, 0, stream>>>(part, cls_b, box_b, o_logits, o_probs, o_bbox);

    // 7) mw1 = leaky(cls_w @ tf1_w^T + tf1_b)   [full-K, fused epilogue]
    gemm_nt<64, 64, 4, 4><<<32, 256, 0, stream>>>(
        cls_w, tf1_w, tf1_b, mw1, 81, 1024, 1024, 1024, 1024, 16);

    // 8) mw = leaky(mw1 @ tf2_w^T + tf2_b)      [full-K, fused epilogue]
    gemm_nt<64, 64, 4, 4><<<8, 256, 0, stream>>>(
        mw1, tf2_w, tf2_b, o_mw, 81, 256, 1024, 1024, 1024, 4);
}

// Round 7
// 434.212 us; speedup vs baseline: 1.2252x; 1.2252x over previous
//
#include <hip/hip_runtime.h>
#include <math.h>

// B=2, N=512, C=256, POOL=7, NC=81, IMG=1024 ; M = 1024 rois, K1 = 12544
static constexpr int K1 = 12544;

typedef __attribute__((ext_vector_type(8))) _Float16 f16x8;
typedef __attribute__((ext_vector_type(4))) _Float16 f16x4;
typedef __attribute__((ext_vector_type(4))) float f32x4;

// ---------------- ws layout (byte offsets) ----------------
static constexpr size_t REG0_OFF = 0;
static constexpr size_t W1_OFF   = 25690112;   // 25.69 MB fp16 w1
static constexpr size_t PART_OFF = 51380224;   // 32 MB split-K partials
static constexpr size_t H1_OFF   = 84934656;   // 4 MB fp32
// inside REG0, valid only after conv1 gemm has consumed ph:
static constexpr size_t S1H_OFF  = 0;          // 2 MB fp16
static constexpr size_t S2H_OFF  = 2097152;    // 2 MB fp16
static constexpr size_t W2H_OFF  = 4194304;    // 2 MB fp16
static constexpr size_t WCAT_OFF = 6291456;    // 1 MB fp16 (512x1024)
static constexpr size_t MW1_OFF  = 7340032;    // 0.33 MB fp32
static constexpr size_t STAT_OFF = 7671808;    // bn stats (written AFTER conv1)

// ---------------------------------------------------------------------------
__device__ __forceinline__ void gload16(const void* g, void* l) {
    __builtin_amdgcn_global_load_lds(
        (const __attribute__((address_space(1))) void*)g,
        (__attribute__((address_space(3))) void*)l, 16, 0, 0);
}

// ---------------------------------------------------------------------------
// prep: blocks [0,12544) ROI-align gather -> ph fp16 (geometry inline,
//   lane-pair x-column scheme, 8 ch/thread). blocks [12544,25088) cvt w1.
// ---------------------------------------------------------------------------
__global__ __launch_bounds__(256) void prep_k(
    const float* __restrict__ p2, const float* __restrict__ p3,
    const float* __restrict__ p4, const float* __restrict__ p5,
    const float* __restrict__ rois, _Float16* __restrict__ ph,
    const float* __restrict__ w1, _Float16* __restrict__ w1h)
{
    if (blockIdx.x >= 12544) {
        int i = (blockIdx.x - 12544) * 256 + threadIdx.x;   // < 3211264
        float4 v = ((const float4*)w1)[i];
        f16x4 h;
        h.x = (_Float16)v.x; h.y = (_Float16)v.y;
        h.z = (_Float16)v.z; h.w = (_Float16)v.w;
        ((f16x4*)w1h)[i] = h;
        return;
    }
    const int q  = threadIdx.x & 1;                 // x-column select
    const int gp = blockIdx.x * 128 + (threadIdx.x >> 1);   // pair id
    const int n  = gp / 1568;                       // 1568 = 49 pos * 32 cgroups
    const int r  = gp - n * 1568;
    const int cg = r / 49;
    const int pos = r - cg * 49;
    const int px = pos % 7, py = pos / 7;

    // inline geometry (8x redundant across cgroups -- hidable under HBM)
    float4 rr = ((const float4*)rois)[n];   // (x1, y1, x2, y2)
    float area = (rr.w - rr.y) * (rr.z - rr.x);
    float lf = rintf(log2f(sqrtf(area) / 224.f)) + 4.f;
    int li = (int)fminf(fmaxf(lf, 2.f), 5.f);
    int H = 256 >> (li - 2);

    const float* f; int sh;
    if (li <= 2)      { f = p2; sh = 16; }
    else if (li == 3) { f = p3; sh = 14; }
    else if (li == 4) { f = p4; sh = 12; }
    else              { f = p5; sh = 10; }

    const float inv = 1.f / 1024.f;
    float by1 = rr.y * inv, bx1 = rr.x * inv, by2 = rr.w * inv, bx2 = rr.z * inv;
    float Hm1 = (float)(H - 1);
    float gy = (float)py / 6.f;
    float gx = (float)px / 6.f;
    float ys = (by1 + gy * (by2 - by1)) * Hm1;
    float xs = (bx1 + gx * (bx2 - bx1)) * Hm1;
    float y0f = floorf(ys), x0f = floorf(xs);
    float ly = ys - y0f, lx = xs - x0f;
    int iy0 = (int)fminf(fmaxf(y0f,       0.f), Hm1);
    int iy1 = (int)fminf(fmaxf(y0f + 1.f, 0.f), Hm1);
    int ix  = q ? (int)fminf(fmaxf(x0f + 1.f, 0.f), Hm1)
                : (int)fminf(fmaxf(x0f,       0.f), Hm1);
    bool valid = (ys >= 0.f) && (ys <= Hm1) && (xs >= 0.f) && (xs <= Hm1);
    float vm = valid ? 1.f : 0.f;
    float wx = q ? lx : (1.f - lx);
    const float w0  = (1.f - ly) * wx * vm;
    const float w1w = ly * wx * vm;
    const int off0 = iy0 * H + ix;
    const int off1 = iy1 * H + ix;

    const size_t cs = (size_t)1 << sh;              // channel stride (floats)
    const float* fb = f + (size_t)(cg * 8) * cs;

    float v0[8], v1[8];
    #pragma unroll
    for (int cc = 0; cc < 8; cc++) {
        v0[cc] = fb[(size_t)cc * cs + off0];
        v1[cc] = fb[(size_t)cc * cs + off1];
    }

    _Float16* pb = ph + (size_t)n * 12544 + (size_t)(cg * 8) * 49 + pos;
    #pragma unroll
    for (int cc = 0; cc < 8; cc++) {
        float t = v0[cc] * w0 + v1[cc] * w1w;
        t += __shfl_xor(t, 1);                      // combine x0+x1 columns
        if ((cc >> 2) == q) pb[cc * 49] = (_Float16)t;
    }
}

// ---------------------------------------------------------------------------
// fp16 MFMA GEMM: Cpart[s] = Ah * Bh^T (per-split chunk), plain stores.
// 128x128 tile, 4 waves (2x2 of 64x64), BK=64, 8-slot XOR-swizzled LDS.
// MODE 0 (grid 8*tilesN): tm=bx&7 (A-panel pinned to XCD bx&7).
// MODE 1 (grid 64 = 8x8 tiles): 2x4 panel-block decode — XCD x owns tile
//   region rows{2r,2r+1} x cols{4c..4c+3}, r=x>>1,c=x&1. Cuts L2-miss
//   traffic from A*1+B*8 to A*2+B*4 panels (230->154MB for conv1).
// kChunk must be a multiple of 64.
// ---------------------------------------------------------------------------
template<int MODE>
__global__ __launch_bounds__(256) void gemm16h(
    const _Float16* __restrict__ Ah, const _Float16* __restrict__ Bh,
    float* __restrict__ Cpart, int Nn, int lda, int ldb, int kChunk)
{
    __shared__ _Float16 sA[128][64];
    __shared__ _Float16 sB[128][64];

    const int tid  = threadIdx.x;
    const int lane = tid & 63;
    const int wave = tid >> 6;
    int tm, tn;
    if constexpr (MODE == 0) {
        tm = blockIdx.x & 7;  tn = blockIdx.x >> 3;
    } else {
        const int x = blockIdx.x & 7;       // == XCD (round-robin, gridX%8==0)
        const int t = blockIdx.x >> 3;      // 0..7 within region
        tm = (((x >> 1) << 1) | (t & 1));
        tn = (((x & 1) << 2) | (t >> 1));
    }
    const int tm0 = tm * 128;
    const int tn0 = tn * 128;
    const int k0  = blockIdx.y * kChunk;

    const int wm = (wave >> 1) * 64;
    const int wn = (wave & 1) * 64;

    const int r8  = lane >> 3;
    const int skh = ((lane & 7) ^ r8) * 8;          // halfs

    f32x4 acc[4][4];
    #pragma unroll
    for (int i = 0; i < 4; i++)
        #pragma unroll
        for (int j = 0; j < 4; j++) acc[i][j] = (f32x4){0.f, 0.f, 0.f, 0.f};

    const int mrow = wm + (lane & 15);
    const int ncol = wn + (lane & 15);
    const int gk   = lane >> 4;                     // k-subgroup 0..3
    const int swz  = lane & 7;                      // == mrow&7 == ncol&7

    for (int kt = 0; kt < kChunk; kt += 64) {
        const int kb = k0 + kt;
        #pragma unroll
        for (int i = 0; i < 4; i++) {
            const int rr = wave * 32 + i * 8 + r8;
            gload16(Ah + (size_t)(tm0 + rr) * lda + kb + skh, &sA[wave * 32 + i * 8][0]);
            gload16(Bh + (size_t)(tn0 + rr) * ldb + kb + skh, &sB[wave * 32 + i * 8][0]);
        }
        __syncthreads();

        f16x8 fa[2][4], fb[2][4];
        #pragma unroll
        for (int kk = 0; kk < 2; kk++) {
            const int sc = ((kk * 4 + gk) ^ swz) * 8;   // swizzled halfs col
            #pragma unroll
            for (int t2 = 0; t2 < 4; t2++) {
                fa[kk][t2] = *(const f16x8*)&sA[mrow + t2 * 16][sc];
                fb[kk][t2] = *(const f16x8*)&sB[ncol + t2 * 16][sc];
            }
        }
        #pragma unroll
        for (int kk = 0; kk < 2; kk++)
            #pragma unroll
            for (int i = 0; i < 4; i++)
                #pragma unroll
                for (int j = 0; j < 4; j++)
                    acc[i][j] = __builtin_amdgcn_mfma_f32_16x16x32_f16(
                        fa[kk][i], fb[kk][j], acc[i][j], 0, 0, 0);
        __syncthreads();
    }

    // C/D layout: col = lane&15, row = (lane>>4)*4 + reg
    float* Cs = Cpart + (size_t)blockIdx.y * 1024 * Nn;
    const int crow = tm0 + wm + (lane >> 4) * 4;
    const int ccol = tn0 + wn + (lane & 15);
    #pragma unroll
    for (int i = 0; i < 4; i++)
        #pragma unroll
        for (int j = 0; j < 4; j++) {
            float* cp = Cs + (size_t)(crow + i * 16) * Nn + (ccol + j * 16);
            #pragma unroll
            for (int rg = 0; rg < 4; rg++)
                cp[(size_t)rg * Nn] = acc[i][j][rg];
        }
}

// ---------------------------------------------------------------------------
// combine NS split-K partials -> h1 (1024x1024), fused bn partial sums.
// grid (4 colgroups, 64 rowgroups of 16 rows), 256 thr.
// ---------------------------------------------------------------------------
template<int NS>
__global__ __launch_bounds__(256) void combine_bn_k(
    const float* __restrict__ part, float* __restrict__ h1,
    float* __restrict__ psum, float* __restrict__ psq)
{
    int col = blockIdx.x * 256 + threadIdx.x;
    int r0  = blockIdx.y * 16;
    float s = 0.f, q = 0.f;
    for (int r = 0; r < 16; r++) {
        const float* p0 = part + (size_t)(r0 + r) * 1024 + col;
        float v = p0[0];
        #pragma unroll
        for (int p = 1; p < NS; p++) v += p0[(size_t)p * 1048576];
        h1[(size_t)(r0 + r) * 1024 + col] = v;
        s += v; q += v * v;
    }
    psum[blockIdx.y * 1024 + col] = s;
    psq [blockIdx.y * 1024 + col] = q;
}

__global__ __launch_bounds__(256) void bn_finalize(
    const float* __restrict__ psum, const float* __restrict__ psq,
    const float* __restrict__ g, const float* __restrict__ b,
    float* __restrict__ scale, float* __restrict__ shift)
{
    int col = blockIdx.x * 256 + threadIdx.x;   // gridDim.x = 4
    float s = 0.f, q = 0.f;
    #pragma unroll
    for (int p = 0; p < 64; p++) { s += psum[p * 1024 + col]; q += psq[p * 1024 + col]; }
    float mean = s * (1.f / 1024.f);
    float var  = q * (1.f / 1024.f) - mean * mean;
    float sc = (1.f / sqrtf(var + 0.001f)) * g[col];
    scale[col] = sc;
    shift[col] = b[col] - mean * sc;
}

// bn+relu -> fp16 ; blocks >= 4096 optionally convert w2/cls/box -> fp16
__global__ __launch_bounds__(256) void bn_apply_cvt_k(
    const float* __restrict__ h, const float* __restrict__ scale,
    const float* __restrict__ shift, _Float16* __restrict__ o16,
    const float* __restrict__ w2, const float* __restrict__ cls,
    const float* __restrict__ box, _Float16* __restrict__ w2h,
    _Float16* __restrict__ wcat)
{
    if (blockIdx.x >= 4096) {
        int i = (blockIdx.x - 4096) * 256 + threadIdx.x;
        const int n_w2 = 262144, n_cls = 20736, n_box = 82944;  // float4 units
        const float* src; _Float16* dst; int j;
        if (i < n_w2)               { src = w2;  dst = w2h;              j = i; }
        else if (i < n_w2 + n_cls)  { src = cls; dst = wcat;             j = i - n_w2; }
        else if (i < n_w2 + n_cls + n_box) { src = box; dst = wcat + 81 * 1024; j = i - n_w2 - n_cls; }
        else return;
        float4 v = ((const float4*)src)[j];
        f16x4 hh;
        hh.x = (_Float16)v.x; hh.y = (_Float16)v.y;
        hh.z = (_Float16)v.z; hh.w = (_Float16)v.w;
        ((f16x4*)dst)[j] = hh;
        return;
    }
    int idx = blockIdx.x * 256 + threadIdx.x;
    int col = idx & 1023;
    float v = fmaxf(h[idx] * scale[col] + shift[col], 0.f);
    o16[idx] = (_Float16)v;
}

// ---------------------------------------------------------------------------
// head combine: sum 8 partials (1024x512), add cls/box bias, route to
// logits/bbox, and compute softmax -> probs. One wave per row, 4 rows/block.
// ---------------------------------------------------------------------------
__global__ __launch_bounds__(256) void head_combine_k(
    const float* __restrict__ part, const float* __restrict__ cls_b,
    const float* __restrict__ box_b, float* __restrict__ o_logits,
    float* __restrict__ o_probs, float* __restrict__ o_bbox)
{
    int wave = threadIdx.x >> 6, lane = threadIdx.x & 63;
    int row = blockIdx.x * 4 + wave;
    const float* pr = part + (size_t)row * 512;

    float lv0;
    {
        float s = pr[lane];
        #pragma unroll
        for (int p = 1; p < 8; p++) s += pr[(size_t)p * 524288 + lane];
        s += cls_b[lane];
        lv0 = s;
        o_logits[(size_t)row * 81 + lane] = s;
    }
    float lv1 = -INFINITY;
    for (int c = lane + 64; c < 405; c += 64) {
        float s = pr[c];
        #pragma unroll
        for (int p = 1; p < 8; p++) s += pr[(size_t)p * 524288 + c];
        if (c < 81) {
            s += cls_b[c];
            lv1 = s;
            o_logits[(size_t)row * 81 + c] = s;
        } else {
            s += box_b[c - 81];
            o_bbox[(size_t)row * 324 + (c - 81)] = s;
        }
    }
    float m = fmaxf(lv0, lv1);
    for (int o = 32; o; o >>= 1) m = fmaxf(m, __shfl_xor(m, o));
    float e0 = expf(lv0 - m);
    float e1 = (lane < 17) ? expf(lv1 - m) : 0.f;
    float s = e0 + e1;
    for (int o = 32; o; o >>= 1) s += __shfl_xor(s, o);
    float rs = 1.f / s;
    o_probs[(size_t)row * 81 + lane] = e0 * rs;
    if (lane < 17) o_probs[(size_t)row * 81 + lane + 64] = e1 * rs;
}

// ---------------------------------------------------------------------------
// fp32 tiled GEMM (tf path): C = A * B^T, split-K partials
// ---------------------------------------------------------------------------
template<int BM, int BN, int TM, int TN>
__global__ __launch_bounds__(256) void gemm_nt(
    const float* __restrict__ A, const float* __restrict__ B,
    float* __restrict__ Cpart,
    int Mm, int Nn, int lda, int ldb, int kChunk, int tilesN)
{
    constexpr int BK = 16;
    __shared__ float As[BK][BM + 4];
    __shared__ float Bs[BK][BN + 4];

    const int tile = blockIdx.x;
    const int s    = blockIdx.y;
    const int tm0  = (tile / tilesN) * BM;
    const int tn0  = (tile % tilesN) * BN;
    const int k0   = s * kChunk;
    const int tid  = threadIdx.x;
    const int tx   = tid % (BN / TN);
    const int ty   = tid / (BN / TN);

    constexpr int AVEC = BM * BK / (256 * 4);
    constexpr int BVEC = BN * BK / (256 * 4);
    const int lrow = tid >> 2;
    const int lkq  = (tid & 3) * 4;

    float acc[TM][TN];
    #pragma unroll
    for (int i = 0; i < TM; i++)
        #pragma unroll
        for (int j = 0; j < TN; j++) acc[i][j] = 0.f;

    for (int kt = 0; kt < kChunk; kt += BK) {
        #pragma unroll
        for (int v = 0; v < AVEC; v++) {
            int row = lrow + v * 64;
            int gm = tm0 + row;
            float4 val = make_float4(0.f, 0.f, 0.f, 0.f);
            if (gm < Mm) val = *(const float4*)&A[(size_t)gm * lda + k0 + kt + lkq];
            As[lkq + 0][row] = val.x; As[lkq + 1][row] = val.y;
            As[lkq + 2][row] = val.z; As[lkq + 3][row] = val.w;
        }
        #pragma unroll
        for (int v = 0; v < BVEC; v++) {
            int row = lrow + v * 64;
            int gn = tn0 + row;
            float4 val = make_float4(0.f, 0.f, 0.f, 0.f);
            if (gn < Nn) val = *(const float4*)&B[(size_t)gn * ldb + k0 + kt + lkq];
            Bs[lkq + 0][row] = val.x; Bs[lkq + 1][row] = val.y;
            Bs[lkq + 2][row] = val.z; Bs[lkq + 3][row] = val.w;
        }
        __syncthreads();
        #pragma unroll
        for (int kk = 0; kk < BK; kk++) {
            float a[TM], b[TN];
            #pragma unroll
            for (int i = 0; i < TM; i++) a[i] = As[kk][ty * TM + i];
            #pragma unroll
            for (int j = 0; j < TN; j++) b[j] = Bs[kk][tx * TN + j];
            #pragma unroll
            for (int i = 0; i < TM; i++)
                #pragma unroll
                for (int j = 0; j < TN; j++)
                    acc[i][j] += a[i] * b[j];
        }
        __syncthreads();
    }

    float* Cs = Cpart + (size_t)s * Mm * Nn;
    #pragma unroll
    for (int i = 0; i < TM; i++) {
        int gm = tm0 + ty * TM + i;
        if (gm >= Mm) continue;
        #pragma unroll
        for (int j = 0; j < TN; j++) {
            int gn = tn0 + tx * TN + j;
            if (gn < Nn) Cs[(size_t)gm * Nn + gn] = acc[i][j];
        }
    }
}

__global__ __launch_bounds__(256) void combine_k(
    const float* __restrict__ part, const float* __restrict__ bias,
    float* __restrict__ out, int MN, int Nn, int nSplit, int act)
{
    int idx = blockIdx.x * 256 + threadIdx.x;
    if (idx >= MN) return;
    float s = 0.f;
    for (int p = 0; p < nSplit; p++) s += part[(size_t)p * MN + idx];
    s += bias[idx % Nn];
    if (act == 1) s = (s >= 0.f) ? s : 0.01f * s;
    out[idx] = s;
}

// ---------------------------------------------------------------------------
extern "C" void kernel_launch(void* const* d_in, const int* in_sizes, int n_in,
                              void* d_out, int out_size, void* d_ws, size_t ws_size,
                              hipStream_t stream)
{
    const float* p2      = (const float*)d_in[0];
    const float* p3      = (const float*)d_in[1];
    const float* p4      = (const float*)d_in[2];
    const float* p5      = (const float*)d_in[3];
    const float* rois    = (const float*)d_in[4];
    const float* conv1_w = (const float*)d_in[5];
    const float* bn1_g   = (const float*)d_in[7];
    const float* bn1_b   = (const float*)d_in[8];
    const float* conv2_w = (const float*)d_in[9];
    const float* bn2_g   = (const float*)d_in[11];
    const float* bn2_b   = (const float*)d_in[12];
    const float* cls_w   = (const float*)d_in[13];
    const float* cls_b   = (const float*)d_in[14];
    const float* box_w   = (const float*)d_in[15];
    const float* box_b   = (const float*)d_in[16];
    const float* tf1_w   = (const float*)d_in[17];
    const float* tf1_b   = (const float*)d_in[18];
    const float* tf2_w   = (const float*)d_in[19];
    const float* tf2_b   = (const float*)d_in[20];

    char* wsb = (char*)d_ws;
    float* out = (float*)d_out;

    _Float16* ph   = (_Float16*)(wsb + REG0_OFF);
    _Float16* w1h  = (_Float16*)(wsb + W1_OFF);
    float*    part = (float*)(wsb + PART_OFF);
    float*    h1   = (float*)(wsb + H1_OFF);
    _Float16* s1h  = (_Float16*)(wsb + S1H_OFF);
    _Float16* s2h  = (_Float16*)(wsb + S2H_OFF);
    _Float16* w2h  = (_Float16*)(wsb + W2H_OFF);
    _Float16* wcat = (_Float16*)(wsb + WCAT_OFF);
    float*    mw1  = (float*)(wsb + MW1_OFF);
    float*    psum = (float*)(wsb + STAT_OFF);
    float*    psq  = psum + 64 * 1024;
    float*    scale = psq + 64 * 1024;
    float*    shift = scale + 1024;

    float* o_logits = out;
    float* o_probs  = out + 82944;
    float* o_bbox   = out + 165888;
    float* o_mw     = out + 497664;

    // 1) ROI gather (inline geometry) + cvt w1
    prep_k<<<25088, 256, 0, stream>>>(p2, p3, p4, p5, rois, ph, conv1_w, w1h);

    // 2) conv1: part[s] = ph @ w1h^T  (split-K=7, kChunk=1792=28*64, 2x4 decode)
    gemm16h<1><<<dim3(64, 7), 256, 0, stream>>>(ph, w1h, part, 1024, K1, K1, 1792);

    // 3) combine + bn1 partial ; finalize ; apply->s1h + cvt w2/cls/box
    combine_bn_k<7><<<dim3(4, 64), 256, 0, stream>>>(part, h1, psum, psq);
    bn_finalize<<<4, 256, 0, stream>>>(psum, psq, bn1_g, bn1_b, scale, shift);
    bn_apply_cvt_k<<<5525, 256, 0, stream>>>(h1, scale, shift, s1h,
                                             conv2_w, cls_w, box_w, w2h, wcat);

    // 4) conv2: part[s] = s1h @ w2h^T  (split-K=4, kChunk=256=4*64, 2x4 decode)
    gemm16h<1><<<dim3(64, 4), 256, 0, stream>>>(s1h, w2h, part, 1024, 1024, 1024, 256);

    // 5) combine + bn2 ; apply -> s2h
    combine_bn_k<4><<<dim3(4, 64), 256, 0, stream>>>(part, h1, psum, psq);
    bn_finalize<<<4, 256, 0, stream>>>(psum, psq, bn2_g, bn2_b, scale, shift);
    bn_apply_cvt_k<<<4096, 256, 0, stream>>>(h1, scale, shift, s2h,
                                             nullptr, nullptr, nullptr, nullptr, nullptr);

    // 6) head: part[s] = s2h @ wcat^T (N=512 padded, split-K=8, MODE 0)
    gemm16h<0><<<dim3(32, 8), 256, 0, stream>>>(s2h, wcat, part, 512, 1024, 1024, 128);
    head_combine_k<<<256, 256, 0, stream>>>(part, cls_b, box_b, o_logits, o_probs, o_bbox);

    // 7) mw1 = leaky(cls_w @ tf1_w^T + tf1_b)
    gemm_nt<64, 64, 4, 4><<<dim3(32, 4), 256, 0, stream>>>(
        cls_w, tf1_w, part, 81, 1024, 1024, 1024, 256, 16);
    combine_k<<<(82944 + 255) / 256, 256, 0, stream>>>(part, tf1_b, mw1, 82944, 1024, 4, 1);

    // 8) mw = leaky(mw1 @ tf2_w^T + tf2_b)
    gemm_nt<64, 64, 4, 4><<<dim3(8, 8), 256, 0, stream>>>(
        mw1, tf2_w, part, 81, 256, 1024, 1024, 128, 4);
    combine_k<<<(20736 + 255) / 256, 256, 0, stream>>>(part, tf2_b, o_mw, 20736, 256, 8, 1);
}